// Round 6
// baseline (152.184 us; speedup 1.0000x reference)
//
#include <hip/hip_runtime.h>
#include <hip/hip_bf16.h>
#include <stdint.h>

#define T_SEQ 4096
#define CDIM  1024
#define NH    16
#define DHEAD 64
#define BAND  128

typedef __bf16 bf16;
typedef __attribute__((ext_vector_type(8)))  __bf16 bf16x8;
typedef __attribute__((ext_vector_type(4)))  __bf16 bf16x4;
typedef __attribute__((ext_vector_type(4)))  float  f32x4;
typedef __attribute__((ext_vector_type(16))) float  f32x16;

// 0.125 (1/sqrt(64)) * log2(e): folded into Q so attn softmax is pure exp2
#define QSCALE 0.1803368801111204f

__device__ __forceinline__ void async_ld16(const bf16* g, bf16* l) {
    __builtin_amdgcn_global_load_lds(
        (__attribute__((address_space(1))) void*)g,
        (__attribute__((address_space(3))) void*)l, 16, 0, 0);
}

// ---------------------------------------------------------------------------
// fp32 -> bf16, 8 elems/thread: x (4194304) + [Wq;Wk;Wv] (3145728)
// ---------------------------------------------------------------------------
__global__ void cvt_all(const float* __restrict__ x,  const float* __restrict__ wq,
                        const float* __restrict__ wk, const float* __restrict__ wv,
                        bf16* __restrict__ xb, bf16* __restrict__ wqkvb) {
    size_t g = (size_t)blockIdx.x * 256 + threadIdx.x;
    const float* s; bf16* d;
    if (g < 524288) {
        s = x + g * 8; d = xb + g * 8;
    } else {
        size_t i2 = (g - 524288) * 8;
        int which = (int)(i2 >> 20);
        s = ((which == 0) ? wq : (which == 1) ? wk : wv) + (i2 & 1048575);
        d = wqkvb + i2;
    }
    const float4* sv = (const float4*)s;
    float4 a = sv[0], b = sv[1];
    bf16x8 o;
    o[0] = (bf16)a.x; o[1] = (bf16)a.y; o[2] = (bf16)a.z; o[3] = (bf16)a.w;
    o[4] = (bf16)b.x; o[5] = (bf16)b.y; o[6] = (bf16)b.z; o[7] = (bf16)b.w;
    *(bf16x8*)d = o;
}

// ---------------------------------------------------------------------------
// QKV GEMM: C[m,n] = sum_k A[m,k]*B[n,k]   A=4096x1024 (x), B=3072x1024
// 128x128 tile, BK=64, 4 waves (2x2 of 64x64), 32x32x16 bf16 MFMA,
// 8-slot XOR-swizzled LDS rows (conflict-free b128 frag reads).
// ---------------------------------------------------------------------------
__global__ __launch_bounds__(256) void gemm_qkv(
        const bf16* __restrict__ A, const bf16* __restrict__ B,
        bf16* __restrict__ qb, bf16* __restrict__ kb, bf16* __restrict__ vtb) {
    const int K = 1024;
    __shared__ __align__(16) bf16 lds_a[128 * 64];
    __shared__ __align__(16) bf16 lds_b[128 * 64];
    int t = threadIdx.x;
    int w = t >> 6, l = t & 63;
    int e31 = l & 31, h2 = l >> 5;
    int bx = blockIdx.x;
    int bm = bx & 31, bn = bx >> 5;          // 32 x 24 blocks
    int m0 = bm * 128, n0 = bn * 128;
    int wm = (w >> 1) * 64, wn = (w & 1) * 64;

    f32x16 acc[2][2];
#pragma unroll
    for (int i = 0; i < 2; i++)
#pragma unroll
        for (int j = 0; j < 2; j++)
#pragma unroll
            for (int r = 0; r < 16; r++) acc[i][j][r] = 0.f;

    int row_s[4], ko_s[4];
#pragma unroll
    for (int it = 0; it < 4; it++) {
        int cid = it * 256 + t;
        row_s[it] = cid >> 3;
        ko_s[it] = ((cid & 7) ^ (row_s[it] & 7)) * 8;
    }
    int rowa0 = wm + e31, rowa1 = wm + 32 + e31;
    int rowb0 = wn + e31, rowb1 = wn + 32 + e31;
    int sa0 = rowa0 & 7, sa1 = rowa1 & 7, sb0 = rowb0 & 7, sb1 = rowb1 & 7;
    const bf16* ba0 = lds_a + rowa0 * 64;
    const bf16* ba1 = lds_a + rowa1 * 64;
    const bf16* bb0 = lds_b + rowb0 * 64;
    const bf16* bb1 = lds_b + rowb1 * 64;

    for (int k0 = 0; k0 < K; k0 += 64) {
#pragma unroll
        for (int it = 0; it < 4; it++) {
            bf16* dst_a = lds_a + (it * 256 + w * 64) * 8;
            bf16* dst_b = lds_b + (it * 256 + w * 64) * 8;
            async_ld16(A + (size_t)(m0 + row_s[it]) * K + k0 + ko_s[it], dst_a);
            async_ld16(B + (size_t)(n0 + row_s[it]) * K + k0 + ko_s[it], dst_b);
        }
        __syncthreads();
#pragma unroll
        for (int kk = 0; kk < 4; kk++) {
            int lc = kk * 2 + h2;
            bf16x8 a0 = *(const bf16x8*)(ba0 + ((lc ^ sa0) * 8));
            bf16x8 a1 = *(const bf16x8*)(ba1 + ((lc ^ sa1) * 8));
            bf16x8 b0 = *(const bf16x8*)(bb0 + ((lc ^ sb0) * 8));
            bf16x8 b1 = *(const bf16x8*)(bb1 + ((lc ^ sb1) * 8));
            acc[0][0] = __builtin_amdgcn_mfma_f32_32x32x16_bf16(a0, b0, acc[0][0], 0, 0, 0);
            acc[0][1] = __builtin_amdgcn_mfma_f32_32x32x16_bf16(a0, b1, acc[0][1], 0, 0, 0);
            acc[1][0] = __builtin_amdgcn_mfma_f32_32x32x16_bf16(a1, b0, acc[1][0], 0, 0, 0);
            acc[1][1] = __builtin_amdgcn_mfma_f32_32x32x16_bf16(a1, b1, acc[1][1], 0, 0, 0);
        }
        __syncthreads();
    }

    if (n0 < 2048) {
        bool isQ = (n0 < 1024);
        bf16* dst = isQ ? qb : kb;
        float scale = isQ ? QSCALE : 1.0f;
        int obase = n0 & 1023;
#pragma unroll
        for (int i = 0; i < 2; i++)
#pragma unroll
            for (int j = 0; j < 2; j++) {
                int o = obase + wn + j * 32 + e31;
                int h = o >> 6, d = o & 63;
#pragma unroll
                for (int r = 0; r < 16; r++) {
                    int trow = m0 + wm + i * 32 + (r & 3) + 8 * (r >> 2) + 4 * h2;
                    dst[((size_t)(h * T_SEQ + trow)) * 64 + d] = (bf16)(acc[i][j][r] * scale);
                }
            }
    } else {
        int obase = n0 - 2048;
#pragma unroll
        for (int i = 0; i < 2; i++)
#pragma unroll
            for (int j = 0; j < 2; j++) {
                int o = obase + wn + j * 32 + e31;       // h*64+d
                size_t base = (size_t)o * T_SEQ;
#pragma unroll
                for (int rq = 0; rq < 4; rq++) {
                    int tbase = m0 + wm + i * 32 + 8 * rq + 4 * h2;
                    bf16x4 pk;
#pragma unroll
                    for (int rr = 0; rr < 4; rr++) pk[rr] = (bf16)acc[i][j][rq * 4 + rr];
                    *(bf16x4*)(vtb + base + tbase) = pk;
                }
            }
    }
}

// ---------------------------------------------------------------------------
// Banded attention: block = (head, 64 q-rows), 4 waves of 16 rows each;
// per-wave key window [rowbase-128, rowbase+16) = 9 x 16 tiles (144 keys,
// only 12.5% over the 128 live keys/row). 1024 blocks = 4/CU.
// Q pre-scaled by 0.125*log2e -> softmax = plain exp2 sum, no max-subtract.
// PV: P padded with zeros to 160 cols so the 5x32-key k-loop stays aligned
// (V over-read lands in adjacent ws memory, multiplied by P=0).
// Prologue (first 512 blocks): Wo fp32->bf16.
// ---------------------------------------------------------------------------
#define PSTR 168

__global__ __launch_bounds__(256) void attn(
        const bf16* __restrict__ qbuf, const bf16* __restrict__ kbuf,
        const bf16* __restrict__ vtbuf, bf16* __restrict__ yb,
        const float* __restrict__ wo, bf16* __restrict__ wob) {
    __shared__ __align__(16) bf16 p_lds[4 * 16 * PSTR];   // 21 KB
    int t = threadIdx.x;
    int w = t >> 6, l = t & 63;
    int quad = l >> 4, col = l & 15;

    if (blockIdx.x < 512) {   // Wo conversion: 512 x 256 x 8 = 1048576
        size_t g = ((size_t)blockIdx.x * 256 + t) * 8;
        const float4* sv = (const float4*)(wo + g);
        float4 a = sv[0], b = sv[1];
        bf16x8 o8;
        o8[0] = (bf16)a.x; o8[1] = (bf16)a.y; o8[2] = (bf16)a.z; o8[3] = (bf16)a.w;
        o8[4] = (bf16)b.x; o8[5] = (bf16)b.y; o8[6] = (bf16)b.z; o8[7] = (bf16)b.w;
        *(bf16x8*)(wob + g) = o8;
    }

    int h = blockIdx.x >> 6;      // 16 heads
    int qt = blockIdx.x & 63;     // 64-row q tiles
    int i0 = qt * 64;
    int rowbase = i0 + w * 16;
    int jbase = rowbase - 128;

    const bf16* Q  = qbuf  + (size_t)h * T_SEQ * 64;
    const bf16* Kp = kbuf  + (size_t)h * T_SEQ * 64;
    const bf16* Vt = vtbuf + (size_t)h * 64 * T_SEQ;

    // Q fragment (A-layout): m=col, k=quad*8+e, two 32-key k-chunks
    bf16x8 qf[2];
#pragma unroll
    for (int kk = 0; kk < 2; kk++)
        qf[kk] = *(const bf16x8*)(Q + (size_t)(rowbase + col) * 64 + kk * 32 + quad * 8);

    f32x4 s[9];
#pragma unroll
    for (int nj = 0; nj < 9; nj++) s[nj] = (f32x4){0.f, 0.f, 0.f, 0.f};
#pragma unroll
    for (int nj = 0; nj < 9; nj++) {
        int jr = jbase + nj * 16 + col;
        int jl = jr < 0 ? 0 : jr;
#pragma unroll
        for (int kk = 0; kk < 2; kk++) {
            bf16x8 kf = *(const bf16x8*)(Kp + (size_t)jl * 64 + kk * 32 + quad * 8);
            s[nj] = __builtin_amdgcn_mfma_f32_16x16x32_bf16(qf[kk], kf, s[nj], 0, 0, 0);
        }
    }

    // mask + exp2 + row-sum (no max-subtract; scores are O(1) in log2 domain)
    float l_run[4];
#pragma unroll
    for (int r = 0; r < 4; r++) {
        int ii = rowbase + quad * 4 + r;
        float rs = 0.f;
#pragma unroll
        for (int nj = 0; nj < 9; nj++) {
            int jj = jbase + nj * 16 + col;
            bool ok = (jj >= 0) && ((unsigned)(ii - jj) < (unsigned)BAND);
            float p = ok ? __builtin_amdgcn_exp2f(s[nj][r]) : 0.f;
            s[nj][r] = p;
            rs += p;
        }
        rs += __shfl_xor(rs, 1);
        rs += __shfl_xor(rs, 2);
        rs += __shfl_xor(rs, 4);
        rs += __shfl_xor(rs, 8);
        l_run[r] = rs;
    }

    // P -> per-wave LDS (C/D-layout scatter), zero-pad cols 144..159
    bf16* myp = p_lds + w * (16 * PSTR);
#pragma unroll
    for (int nj = 0; nj < 9; nj++)
#pragma unroll
        for (int r = 0; r < 4; r++)
            myp[(quad * 4 + r) * PSTR + nj * 16 + col] = (bf16)s[nj][r];
    {
        int zr = l >> 2, zc = 144 + (l & 3) * 4;
        *(bf16x4*)(myp + zr * PSTR + zc) = (bf16x4){(bf16)0.f, (bf16)0.f, (bf16)0.f, (bf16)0.f};
    }

    // O = P(16x160) V(160x64)
    f32x4 o_acc[4];
#pragma unroll
    for (int di = 0; di < 4; di++) o_acc[di] = (f32x4){0.f, 0.f, 0.f, 0.f};
#pragma unroll
    for (int kj = 0; kj < 5; kj++) {
        int jv = jbase + kj * 32 + quad * 8;
        int jvc = jv < 0 ? 0 : jv;
        bf16x8 pf = *(const bf16x8*)(myp + col * PSTR + kj * 32 + quad * 8);
#pragma unroll
        for (int di = 0; di < 4; di++) {
            bf16x8 vf = *(const bf16x8*)(Vt + (size_t)(di * 16 + col) * T_SEQ + jvc);
            o_acc[di] = __builtin_amdgcn_mfma_f32_16x16x32_bf16(pf, vf, o_acc[di], 0, 0, 0);
        }
    }

#pragma unroll
    for (int di = 0; di < 4; di++)
#pragma unroll
        for (int r = 0; r < 4; r++) {
            int tt = rowbase + quad * 4 + r;
            int c = h * 64 + di * 16 + col;
            yb[(size_t)tt * CDIM + c] = (bf16)(o_acc[di][r] / l_run[r]);
        }
}

// ---------------------------------------------------------------------------
// Output projection: out[t,o] = sum_c y[t,c]*Wo[o,c], fp32 out.
// 64x128 tile, BK=64 -> 512 blocks; 4 waves as 2x2 of (32m x 64n); 32x32x16.
// ---------------------------------------------------------------------------
__global__ __launch_bounds__(256) void gemm_proj(
        const bf16* __restrict__ A, const bf16* __restrict__ B,
        float* __restrict__ Cout) {
    const int K = 1024;
    __shared__ __align__(16) bf16 lds_a[64 * 64];
    __shared__ __align__(16) bf16 lds_b[128 * 64];
    int t = threadIdx.x;
    int w = t >> 6, l = t & 63;
    int e31 = l & 31, h2 = l >> 5;
    int bx = blockIdx.x;
    int bm = bx & 63, bn = bx >> 6;          // 64 x 8 blocks
    int m0 = bm * 64, n0 = bn * 128;
    int wm = (w >> 1) * 32, wn = (w & 1) * 64;

    f32x16 acc[2];
#pragma unroll
    for (int j = 0; j < 2; j++)
#pragma unroll
        for (int r = 0; r < 16; r++) acc[j][r] = 0.f;

    int rowA[2], koA[2], rowB[4], koB[4];
#pragma unroll
    for (int it = 0; it < 2; it++) {
        int cid = it * 256 + t;
        rowA[it] = cid >> 3;
        koA[it] = ((cid & 7) ^ (rowA[it] & 7)) * 8;
    }
#pragma unroll
    for (int it = 0; it < 4; it++) {
        int cid = it * 256 + t;
        rowB[it] = cid >> 3;
        koB[it] = ((cid & 7) ^ (rowB[it] & 7)) * 8;
    }
    int rowa = wm + e31;
    int rowb0 = wn + e31, rowb1 = wn + 32 + e31;
    int sa = rowa & 7, sb0 = rowb0 & 7, sb1 = rowb1 & 7;
    const bf16* ba = lds_a + rowa * 64;
    const bf16* bb0 = lds_b + rowb0 * 64;
    const bf16* bb1 = lds_b + rowb1 * 64;

    for (int k0 = 0; k0 < K; k0 += 64) {
#pragma unroll
        for (int it = 0; it < 2; it++)
            async_ld16(A + (size_t)(m0 + rowA[it]) * K + k0 + koA[it],
                       lds_a + (it * 256 + w * 64) * 8);
#pragma unroll
        for (int it = 0; it < 4; it++)
            async_ld16(B + (size_t)(n0 + rowB[it]) * K + k0 + koB[it],
                       lds_b + (it * 256 + w * 64) * 8);
        __syncthreads();
#pragma unroll
        for (int kk = 0; kk < 4; kk++) {
            int lc = kk * 2 + h2;
            bf16x8 af = *(const bf16x8*)(ba + ((lc ^ sa) * 8));
            bf16x8 b0 = *(const bf16x8*)(bb0 + ((lc ^ sb0) * 8));
            bf16x8 b1 = *(const bf16x8*)(bb1 + ((lc ^ sb1) * 8));
            acc[0] = __builtin_amdgcn_mfma_f32_32x32x16_bf16(af, b0, acc[0], 0, 0, 0);
            acc[1] = __builtin_amdgcn_mfma_f32_32x32x16_bf16(af, b1, acc[1], 0, 0, 0);
        }
        __syncthreads();
    }
#pragma unroll
    for (int j = 0; j < 2; j++) {
        int ncol = n0 + wn + j * 32 + e31;
#pragma unroll
        for (int r = 0; r < 16; r++) {
            int trow = m0 + wm + (r & 3) + 8 * (r >> 2) + 4 * h2;
            Cout[(size_t)trow * CDIM + ncol] = acc[j][r];
        }
    }
}

extern "C" void kernel_launch(void* const* d_in, const int* in_sizes, int n_in,
                              void* d_out, int out_size, void* d_ws, size_t ws_size,
                              hipStream_t stream) {
    const float* x  = (const float*)d_in[0];
    const float* Wq = (const float*)d_in[1];
    const float* Wk = (const float*)d_in[2];
    const float* Wv = (const float*)d_in[3];
    const float* Wo = (const float*)d_in[4];
    float* out = (float*)d_out;

    char* ws = (char*)d_ws;
    bf16* xb    = (bf16*)(ws);                        //  8 MB  x bf16
    bf16* wqkvb = (bf16*)(ws + ((size_t)8  << 20));   //  6 MB  [Wq;Wk;Wv]
    bf16* wob   = (bf16*)(ws + ((size_t)14 << 20));   //  2 MB  Wo
    bf16* qb    = (bf16*)(ws + ((size_t)16 << 20));   //  8 MB  Q (H,T,64), pre-scaled
    bf16* kb    = (bf16*)(ws + ((size_t)24 << 20));   //  8 MB  K (H,T,64)
    bf16* vtb   = (bf16*)(ws + ((size_t)32 << 20));   //  8 MB  V^T (H*64,T)
    bf16* yb    = (bf16*)(ws + ((size_t)40 << 20));   //  8 MB  y (T,C)

    cvt_all<<<3584, 256, 0, stream>>>(x, Wq, Wk, Wv, xb, wqkvb);
    gemm_qkv<<<768, 256, 0, stream>>>(xb, wqkvb, qb, kb, vtb);
    attn<<<1024, 256, 0, stream>>>(qb, kb, vtb, yb, Wo, wob);
    gemm_proj<<<512, 256, 0, stream>>>(yb, wob, out);
}

// Round 7
// 147.744 us; speedup vs baseline: 1.0301x; 1.0301x over previous
//
#include <hip/hip_runtime.h>
#include <hip/hip_bf16.h>
#include <stdint.h>

#define T_SEQ 4096
#define CDIM  1024
#define NH    16
#define DHEAD 64
#define BAND  128

typedef __bf16 bf16;
typedef __attribute__((ext_vector_type(8)))  __bf16 bf16x8;
typedef __attribute__((ext_vector_type(4)))  __bf16 bf16x4;
typedef __attribute__((ext_vector_type(4)))  float  f32x4;
typedef __attribute__((ext_vector_type(16))) float  f32x16;

// 0.125 (1/sqrt(64)) * log2(e): folded into Q so attn softmax is pure exp2
#define QSCALE 0.1803368801111204f

__device__ __forceinline__ void async_ld16(const bf16* g, bf16* l) {
    __builtin_amdgcn_global_load_lds(
        (__attribute__((address_space(1))) void*)g,
        (__attribute__((address_space(3))) void*)l, 16, 0, 0);
}

// ---------------------------------------------------------------------------
// fp32 -> bf16, 8 elems/thread: x (4194304) + [Wq;Wk;Wv] (3145728)
// ---------------------------------------------------------------------------
__global__ void cvt_all(const float* __restrict__ x,  const float* __restrict__ wq,
                        const float* __restrict__ wk, const float* __restrict__ wv,
                        bf16* __restrict__ xb, bf16* __restrict__ wqkvb) {
    size_t g = (size_t)blockIdx.x * 256 + threadIdx.x;
    const float* s; bf16* d;
    if (g < 524288) {
        s = x + g * 8; d = xb + g * 8;
    } else {
        size_t i2 = (g - 524288) * 8;
        int which = (int)(i2 >> 20);
        s = ((which == 0) ? wq : (which == 1) ? wk : wv) + (i2 & 1048575);
        d = wqkvb + i2;
    }
    const float4* sv = (const float4*)s;
    float4 a = sv[0], b = sv[1];
    bf16x8 o;
    o[0] = (bf16)a.x; o[1] = (bf16)a.y; o[2] = (bf16)a.z; o[3] = (bf16)a.w;
    o[4] = (bf16)b.x; o[5] = (bf16)b.y; o[6] = (bf16)b.z; o[7] = (bf16)b.w;
    *(bf16x8*)d = o;
}

// ---------------------------------------------------------------------------
// QKV GEMM: C[m,n] = sum_k A[m,k]*B[n,k]   A=4096x1024 (x), B=3072x1024
// 128x128 tile, BK=64, 4 waves (2x2 of 64x64), 32x32x16 bf16 MFMA,
// 8-slot XOR-swizzled LDS rows (conflict-free b128 frag reads).
// ---------------------------------------------------------------------------
__global__ __launch_bounds__(256) void gemm_qkv(
        const bf16* __restrict__ A, const bf16* __restrict__ B,
        bf16* __restrict__ qb, bf16* __restrict__ kb, bf16* __restrict__ vtb) {
    const int K = 1024;
    __shared__ __align__(16) bf16 lds_a[128 * 64];
    __shared__ __align__(16) bf16 lds_b[128 * 64];
    int t = threadIdx.x;
    int w = t >> 6, l = t & 63;
    int e31 = l & 31, h2 = l >> 5;
    int bx = blockIdx.x;
    int bm = bx & 31, bn = bx >> 5;          // 32 x 24 blocks
    int m0 = bm * 128, n0 = bn * 128;
    int wm = (w >> 1) * 64, wn = (w & 1) * 64;

    f32x16 acc[2][2];
#pragma unroll
    for (int i = 0; i < 2; i++)
#pragma unroll
        for (int j = 0; j < 2; j++)
#pragma unroll
            for (int r = 0; r < 16; r++) acc[i][j][r] = 0.f;

    int row_s[4], ko_s[4];
#pragma unroll
    for (int it = 0; it < 4; it++) {
        int cid = it * 256 + t;
        row_s[it] = cid >> 3;
        ko_s[it] = ((cid & 7) ^ (row_s[it] & 7)) * 8;
    }
    int rowa0 = wm + e31, rowa1 = wm + 32 + e31;
    int rowb0 = wn + e31, rowb1 = wn + 32 + e31;
    int sa0 = rowa0 & 7, sa1 = rowa1 & 7, sb0 = rowb0 & 7, sb1 = rowb1 & 7;
    const bf16* ba0 = lds_a + rowa0 * 64;
    const bf16* ba1 = lds_a + rowa1 * 64;
    const bf16* bb0 = lds_b + rowb0 * 64;
    const bf16* bb1 = lds_b + rowb1 * 64;

    for (int k0 = 0; k0 < K; k0 += 64) {
#pragma unroll
        for (int it = 0; it < 4; it++) {
            bf16* dst_a = lds_a + (it * 256 + w * 64) * 8;
            bf16* dst_b = lds_b + (it * 256 + w * 64) * 8;
            async_ld16(A + (size_t)(m0 + row_s[it]) * K + k0 + ko_s[it], dst_a);
            async_ld16(B + (size_t)(n0 + row_s[it]) * K + k0 + ko_s[it], dst_b);
        }
        __syncthreads();
#pragma unroll
        for (int kk = 0; kk < 4; kk++) {
            int lc = kk * 2 + h2;
            bf16x8 a0 = *(const bf16x8*)(ba0 + ((lc ^ sa0) * 8));
            bf16x8 a1 = *(const bf16x8*)(ba1 + ((lc ^ sa1) * 8));
            bf16x8 b0 = *(const bf16x8*)(bb0 + ((lc ^ sb0) * 8));
            bf16x8 b1 = *(const bf16x8*)(bb1 + ((lc ^ sb1) * 8));
            acc[0][0] = __builtin_amdgcn_mfma_f32_32x32x16_bf16(a0, b0, acc[0][0], 0, 0, 0);
            acc[0][1] = __builtin_amdgcn_mfma_f32_32x32x16_bf16(a0, b1, acc[0][1], 0, 0, 0);
            acc[1][0] = __builtin_amdgcn_mfma_f32_32x32x16_bf16(a1, b0, acc[1][0], 0, 0, 0);
            acc[1][1] = __builtin_amdgcn_mfma_f32_32x32x16_bf16(a1, b1, acc[1][1], 0, 0, 0);
        }
        __syncthreads();
    }

    if (n0 < 2048) {
        bool isQ = (n0 < 1024);
        bf16* dst = isQ ? qb : kb;
        float scale = isQ ? QSCALE : 1.0f;
        int obase = n0 & 1023;
#pragma unroll
        for (int i = 0; i < 2; i++)
#pragma unroll
            for (int j = 0; j < 2; j++) {
                int o = obase + wn + j * 32 + e31;
                int h = o >> 6, d = o & 63;
#pragma unroll
                for (int r = 0; r < 16; r++) {
                    int trow = m0 + wm + i * 32 + (r & 3) + 8 * (r >> 2) + 4 * h2;
                    dst[((size_t)(h * T_SEQ + trow)) * 64 + d] = (bf16)(acc[i][j][r] * scale);
                }
            }
    } else {
        int obase = n0 - 2048;
#pragma unroll
        for (int i = 0; i < 2; i++)
#pragma unroll
            for (int j = 0; j < 2; j++) {
                int o = obase + wn + j * 32 + e31;       // h*64+d
                size_t base = (size_t)o * T_SEQ;
#pragma unroll
                for (int rq = 0; rq < 4; rq++) {
                    int tbase = m0 + wm + i * 32 + 8 * rq + 4 * h2;
                    bf16x4 pk;
#pragma unroll
                    for (int rr = 0; rr < 4; rr++) pk[rr] = (bf16)acc[i][j][rq * 4 + rr];
                    *(bf16x4*)(vtb + base + tbase) = pk;
                }
            }
    }
}

// ---------------------------------------------------------------------------
// Banded attention: block = (head, 128 q-rows), 4 waves of 32 rows;
// per-wave key window [rowbase-128, rowbase+32) = 10 x 16 tiles.
// TRANSPOSED S: S^T = K.Q^T (A=K-frag, B=Q-frag), so each lane holds 4
// consecutive KEYS of one QUERY -> softmax is in-lane + 2 shuffles, 1/l is
// folded into P before the (packed b64) LDS write, no epilogue divide.
// Q pre-scaled by 0.125*log2e -> pure exp2. Prologue: Wo fp32->bf16.
// ---------------------------------------------------------------------------
#define PSTR 168

__global__ __launch_bounds__(256) void attn(
        const bf16* __restrict__ qbuf, const bf16* __restrict__ kbuf,
        const bf16* __restrict__ vtbuf, bf16* __restrict__ yb,
        const float* __restrict__ wo, bf16* __restrict__ wob) {
    __shared__ __align__(16) bf16 p_lds[4 * 32 * PSTR];   // 43 KB
    int t = threadIdx.x;
    int w = t >> 6, l = t & 63;
    int quad = l >> 4, col = l & 15;

    {   // Wo conversion: 512 blocks x 256 thr x 8 = 1048576 exactly
        size_t g = ((size_t)blockIdx.x * 256 + t) * 8;
        const float4* sv = (const float4*)(wo + g);
        float4 a = sv[0], b = sv[1];
        bf16x8 o8;
        o8[0] = (bf16)a.x; o8[1] = (bf16)a.y; o8[2] = (bf16)a.z; o8[3] = (bf16)a.w;
        o8[4] = (bf16)b.x; o8[5] = (bf16)b.y; o8[6] = (bf16)b.z; o8[7] = (bf16)b.w;
        *(bf16x8*)(wob + g) = o8;
    }

    int h = blockIdx.x >> 5;
    int qt = blockIdx.x & 31;
    int i0 = qt * 128;
    int rowbase = i0 + w * 32;
    int jbase = rowbase - 128;

    const bf16* Q  = qbuf  + (size_t)h * T_SEQ * 64;
    const bf16* Kp = kbuf  + (size_t)h * T_SEQ * 64;
    const bf16* Vt = vtbuf + (size_t)h * 64 * T_SEQ;

    // Q fragments (B-operand): n = query = rowbase + nj*16 + col
    bf16x8 qf[2][2];
#pragma unroll
    for (int nj = 0; nj < 2; nj++)
#pragma unroll
        for (int kk = 0; kk < 2; kk++)
            qf[nj][kk] = *(const bf16x8*)(Q + (size_t)(rowbase + nj * 16 + col) * 64 + kk * 32 + quad * 8);

    // S^T[key][query]: s[mi][nj], mi = key tile (10), nj = query tile (2)
    f32x4 s[10][2];
#pragma unroll
    for (int mi = 0; mi < 10; mi++)
#pragma unroll
        for (int nj = 0; nj < 2; nj++) s[mi][nj] = (f32x4){0.f, 0.f, 0.f, 0.f};
#pragma unroll
    for (int mi = 0; mi < 10; mi++) {
        int jr = jbase + mi * 16 + col;
        int jl = jr < 0 ? 0 : jr;
#pragma unroll
        for (int kk = 0; kk < 2; kk++) {
            bf16x8 kf = *(const bf16x8*)(Kp + (size_t)jl * 64 + kk * 32 + quad * 8);
#pragma unroll
            for (int nj = 0; nj < 2; nj++)
                s[mi][nj] = __builtin_amdgcn_mfma_f32_16x16x32_bf16(kf, qf[nj][kk], s[mi][nj], 0, 0, 0);
        }
    }

    // per-query softmax: lane holds keys (mi*16 + quad*4 + r) of query
    // (nj*16+col). In-lane sum of 40 -> xor16/xor32 -> scale by 1/l ->
    // packed bf16x4 store to P[q][j] (2-way bank aliasing only = free).
    bf16* myp = p_lds + w * (32 * PSTR);
#pragma unroll
    for (int nj = 0; nj < 2; nj++) {
        int ii = rowbase + nj * 16 + col;
        float rs = 0.f;
#pragma unroll
        for (int mi = 0; mi < 10; mi++)
#pragma unroll
            for (int r = 0; r < 4; r++) {
                int jj = jbase + mi * 16 + quad * 4 + r;
                bool ok = (jj >= 0) && ((unsigned)(ii - jj) < (unsigned)BAND);
                float p = ok ? __builtin_amdgcn_exp2f(s[mi][nj][r]) : 0.f;
                s[mi][nj][r] = p;
                rs += p;
            }
        rs += __shfl_xor(rs, 16);
        rs += __shfl_xor(rs, 32);
        float inv = 1.0f / rs;
        bf16* qrow = myp + (nj * 16 + col) * PSTR + quad * 4;
#pragma unroll
        for (int mi = 0; mi < 10; mi++) {
            bf16x4 pk;
#pragma unroll
            for (int r = 0; r < 4; r++) pk[r] = (bf16)(s[mi][nj][r] * inv);
            *(bf16x4*)(qrow + mi * 16) = pk;
        }
    }

    // O = P(32x160) V(160x64): A=P from LDS (q=lane&15 rows, j-contig),
    // B=Vt from global. All 160 j-cols of P are written (masked = 0).
    f32x4 o_acc[2][4];
#pragma unroll
    for (int mi2 = 0; mi2 < 2; mi2++)
#pragma unroll
        for (int di = 0; di < 4; di++) o_acc[mi2][di] = (f32x4){0.f, 0.f, 0.f, 0.f};
#pragma unroll
    for (int kj = 0; kj < 5; kj++) {
        int jv = jbase + kj * 32 + quad * 8;
        int jvc = jv < 0 ? 0 : jv;
        bf16x8 pf[2];
#pragma unroll
        for (int mi2 = 0; mi2 < 2; mi2++)
            pf[mi2] = *(const bf16x8*)(myp + (mi2 * 16 + col) * PSTR + kj * 32 + quad * 8);
#pragma unroll
        for (int di = 0; di < 4; di++) {
            bf16x8 vf = *(const bf16x8*)(Vt + (size_t)(di * 16 + col) * T_SEQ + jvc);
#pragma unroll
            for (int mi2 = 0; mi2 < 2; mi2++)
                o_acc[mi2][di] = __builtin_amdgcn_mfma_f32_16x16x32_bf16(pf[mi2], vf, o_acc[mi2][di], 0, 0, 0);
        }
    }

    // y store: P already normalized, no divide
#pragma unroll
    for (int mi2 = 0; mi2 < 2; mi2++)
#pragma unroll
        for (int di = 0; di < 4; di++)
#pragma unroll
            for (int r = 0; r < 4; r++) {
                int tt = rowbase + mi2 * 16 + quad * 4 + r;
                int c = h * 64 + di * 16 + col;
                yb[(size_t)tt * CDIM + c] = (bf16)o_acc[mi2][di][r];
            }
}

// ---------------------------------------------------------------------------
// Output projection: out[t,o] = sum_c y[t,c]*Wo[o,c], fp32 out.
// 64x128 tile, BK=64 -> 512 blocks; 4 waves as 2x2 of (32m x 64n); 32x32x16.
// ---------------------------------------------------------------------------
__global__ __launch_bounds__(256) void gemm_proj(
        const bf16* __restrict__ A, const bf16* __restrict__ B,
        float* __restrict__ Cout) {
    const int K = 1024;
    __shared__ __align__(16) bf16 lds_a[64 * 64];
    __shared__ __align__(16) bf16 lds_b[128 * 64];
    int t = threadIdx.x;
    int w = t >> 6, l = t & 63;
    int e31 = l & 31, h2 = l >> 5;
    int bx = blockIdx.x;
    int bm = bx & 63, bn = bx >> 6;          // 64 x 8 blocks
    int m0 = bm * 64, n0 = bn * 128;
    int wm = (w >> 1) * 32, wn = (w & 1) * 64;

    f32x16 acc[2];
#pragma unroll
    for (int j = 0; j < 2; j++)
#pragma unroll
        for (int r = 0; r < 16; r++) acc[j][r] = 0.f;

    int rowA[2], koA[2], rowB[4], koB[4];
#pragma unroll
    for (int it = 0; it < 2; it++) {
        int cid = it * 256 + t;
        rowA[it] = cid >> 3;
        koA[it] = ((cid & 7) ^ (rowA[it] & 7)) * 8;
    }
#pragma unroll
    for (int it = 0; it < 4; it++) {
        int cid = it * 256 + t;
        rowB[it] = cid >> 3;
        koB[it] = ((cid & 7) ^ (rowB[it] & 7)) * 8;
    }
    int rowa = wm + e31;
    int rowb0 = wn + e31, rowb1 = wn + 32 + e31;
    int sa = rowa & 7, sb0 = rowb0 & 7, sb1 = rowb1 & 7;
    const bf16* ba = lds_a + rowa * 64;
    const bf16* bb0 = lds_b + rowb0 * 64;
    const bf16* bb1 = lds_b + rowb1 * 64;

    for (int k0 = 0; k0 < K; k0 += 64) {
#pragma unroll
        for (int it = 0; it < 2; it++)
            async_ld16(A + (size_t)(m0 + rowA[it]) * K + k0 + koA[it],
                       lds_a + (it * 256 + w * 64) * 8);
#pragma unroll
        for (int it = 0; it < 4; it++)
            async_ld16(B + (size_t)(n0 + rowB[it]) * K + k0 + koB[it],
                       lds_b + (it * 256 + w * 64) * 8);
        __syncthreads();
#pragma unroll
        for (int kk = 0; kk < 4; kk++) {
            int lc = kk * 2 + h2;
            bf16x8 af = *(const bf16x8*)(ba + ((lc ^ sa) * 8));
            bf16x8 b0 = *(const bf16x8*)(bb0 + ((lc ^ sb0) * 8));
            bf16x8 b1 = *(const bf16x8*)(bb1 + ((lc ^ sb1) * 8));
            acc[0] = __builtin_amdgcn_mfma_f32_32x32x16_bf16(af, b0, acc[0], 0, 0, 0);
            acc[1] = __builtin_amdgcn_mfma_f32_32x32x16_bf16(af, b1, acc[1], 0, 0, 0);
        }
        __syncthreads();
    }
#pragma unroll
    for (int j = 0; j < 2; j++) {
        int ncol = n0 + wn + j * 32 + e31;
#pragma unroll
        for (int r = 0; r < 16; r++) {
            int trow = m0 + wm + (r & 3) + 8 * (r >> 2) + 4 * h2;
            Cout[(size_t)trow * CDIM + ncol] = acc[j][r];
        }
    }
}

extern "C" void kernel_launch(void* const* d_in, const int* in_sizes, int n_in,
                              void* d_out, int out_size, void* d_ws, size_t ws_size,
                              hipStream_t stream) {
    const float* x  = (const float*)d_in[0];
    const float* Wq = (const float*)d_in[1];
    const float* Wk = (const float*)d_in[2];
    const float* Wv = (const float*)d_in[3];
    const float* Wo = (const float*)d_in[4];
    float* out = (float*)d_out;

    char* ws = (char*)d_ws;
    bf16* xb    = (bf16*)(ws);                        //  8 MB  x bf16
    bf16* wqkvb = (bf16*)(ws + ((size_t)8  << 20));   //  6 MB  [Wq;Wk;Wv]
    bf16* wob   = (bf16*)(ws + ((size_t)14 << 20));   //  2 MB  Wo
    bf16* qb    = (bf16*)(ws + ((size_t)16 << 20));   //  8 MB  Q (H,T,64), pre-scaled
    bf16* kb    = (bf16*)(ws + ((size_t)24 << 20));   //  8 MB  K (H,T,64)
    bf16* vtb   = (bf16*)(ws + ((size_t)32 << 20));   //  8 MB  V^T (H*64,T)
    bf16* yb    = (bf16*)(ws + ((size_t)40 << 20));   //  8 MB  y (T,C)

    cvt_all<<<3584, 256, 0, stream>>>(x, Wq, Wk, Wv, xb, wqkvb);
    gemm_qkv<<<768, 256, 0, stream>>>(xb, wqkvb, qb, kb, vtb);
    attn<<<512, 256, 0, stream>>>(qb, kb, vtb, yb, Wo, wob);
    gemm_proj<<<512, 256, 0, stream>>>(yb, wob, out);
}

// Round 8
// 145.512 us; speedup vs baseline: 1.0459x; 1.0153x over previous
//
#include <hip/hip_runtime.h>
#include <hip/hip_bf16.h>
#include <stdint.h>

#define T_SEQ 4096
#define CDIM  1024
#define NH    16
#define DHEAD 64
#define BAND  128

typedef __bf16 bf16;
typedef __attribute__((ext_vector_type(8)))  __bf16 bf16x8;
typedef __attribute__((ext_vector_type(4)))  __bf16 bf16x4;
typedef __attribute__((ext_vector_type(4)))  float  f32x4;
typedef __attribute__((ext_vector_type(16))) float  f32x16;

// 0.125 (1/sqrt(64)) * log2(e): folded into Q so attn softmax is pure exp2
#define QSCALE 0.1803368801111204f

__device__ __forceinline__ void async_ld16(const bf16* g, bf16* l) {
    __builtin_amdgcn_global_load_lds(
        (__attribute__((address_space(1))) void*)g,
        (__attribute__((address_space(3))) void*)l, 16, 0, 0);
}

// ---------------------------------------------------------------------------
// fp32 -> bf16, 8 elems/thread: x (4194304) + [Wq;Wk;Wv] (3145728)
// ---------------------------------------------------------------------------
__global__ void cvt_all(const float* __restrict__ x,  const float* __restrict__ wq,
                        const float* __restrict__ wk, const float* __restrict__ wv,
                        bf16* __restrict__ xb, bf16* __restrict__ wqkvb) {
    size_t g = (size_t)blockIdx.x * 256 + threadIdx.x;
    const float* s; bf16* d;
    if (g < 524288) {
        s = x + g * 8; d = xb + g * 8;
    } else {
        size_t i2 = (g - 524288) * 8;
        int which = (int)(i2 >> 20);
        s = ((which == 0) ? wq : (which == 1) ? wk : wv) + (i2 & 1048575);
        d = wqkvb + i2;
    }
    const float4* sv = (const float4*)s;
    float4 a = sv[0], b = sv[1];
    bf16x8 o;
    o[0] = (bf16)a.x; o[1] = (bf16)a.y; o[2] = (bf16)a.z; o[3] = (bf16)a.w;
    o[4] = (bf16)b.x; o[5] = (bf16)b.y; o[6] = (bf16)b.z; o[7] = (bf16)b.w;
    *(bf16x8*)d = o;
}

// ---------------------------------------------------------------------------
// QKV GEMM: C[m,n] = sum_k A[m,k]*B[n,k]   A=4096x1024 (x), B=3072x1024
// 128x128 tile, BK=64, 4 waves (2x2 of 64x64), 32x32x16 bf16 MFMA,
// 8-slot XOR-swizzled LDS rows (conflict-free b128 frag reads).
// ---------------------------------------------------------------------------
__global__ __launch_bounds__(256) void gemm_qkv(
        const bf16* __restrict__ A, const bf16* __restrict__ B,
        bf16* __restrict__ qb, bf16* __restrict__ kb, bf16* __restrict__ vtb) {
    const int K = 1024;
    __shared__ __align__(16) bf16 lds_a[128 * 64];
    __shared__ __align__(16) bf16 lds_b[128 * 64];
    int t = threadIdx.x;
    int w = t >> 6, l = t & 63;
    int e31 = l & 31, h2 = l >> 5;
    int bx = blockIdx.x;
    int bm = bx & 31, bn = bx >> 5;          // 32 x 24 blocks
    int m0 = bm * 128, n0 = bn * 128;
    int wm = (w >> 1) * 64, wn = (w & 1) * 64;

    f32x16 acc[2][2];
#pragma unroll
    for (int i = 0; i < 2; i++)
#pragma unroll
        for (int j = 0; j < 2; j++)
#pragma unroll
            for (int r = 0; r < 16; r++) acc[i][j][r] = 0.f;

    int row_s[4], ko_s[4];
#pragma unroll
    for (int it = 0; it < 4; it++) {
        int cid = it * 256 + t;
        row_s[it] = cid >> 3;
        ko_s[it] = ((cid & 7) ^ (row_s[it] & 7)) * 8;
    }
    int rowa0 = wm + e31, rowa1 = wm + 32 + e31;
    int rowb0 = wn + e31, rowb1 = wn + 32 + e31;
    int sa0 = rowa0 & 7, sa1 = rowa1 & 7, sb0 = rowb0 & 7, sb1 = rowb1 & 7;
    const bf16* ba0 = lds_a + rowa0 * 64;
    const bf16* ba1 = lds_a + rowa1 * 64;
    const bf16* bb0 = lds_b + rowb0 * 64;
    const bf16* bb1 = lds_b + rowb1 * 64;

    for (int k0 = 0; k0 < K; k0 += 64) {
#pragma unroll
        for (int it = 0; it < 4; it++) {
            bf16* dst_a = lds_a + (it * 256 + w * 64) * 8;
            bf16* dst_b = lds_b + (it * 256 + w * 64) * 8;
            async_ld16(A + (size_t)(m0 + row_s[it]) * K + k0 + ko_s[it], dst_a);
            async_ld16(B + (size_t)(n0 + row_s[it]) * K + k0 + ko_s[it], dst_b);
        }
        __syncthreads();
#pragma unroll
        for (int kk = 0; kk < 4; kk++) {
            int lc = kk * 2 + h2;
            bf16x8 a0 = *(const bf16x8*)(ba0 + ((lc ^ sa0) * 8));
            bf16x8 a1 = *(const bf16x8*)(ba1 + ((lc ^ sa1) * 8));
            bf16x8 b0 = *(const bf16x8*)(bb0 + ((lc ^ sb0) * 8));
            bf16x8 b1 = *(const bf16x8*)(bb1 + ((lc ^ sb1) * 8));
            acc[0][0] = __builtin_amdgcn_mfma_f32_32x32x16_bf16(a0, b0, acc[0][0], 0, 0, 0);
            acc[0][1] = __builtin_amdgcn_mfma_f32_32x32x16_bf16(a0, b1, acc[0][1], 0, 0, 0);
            acc[1][0] = __builtin_amdgcn_mfma_f32_32x32x16_bf16(a1, b0, acc[1][0], 0, 0, 0);
            acc[1][1] = __builtin_amdgcn_mfma_f32_32x32x16_bf16(a1, b1, acc[1][1], 0, 0, 0);
        }
        __syncthreads();
    }

    if (n0 < 2048) {
        bool isQ = (n0 < 1024);
        bf16* dst = isQ ? qb : kb;
        float scale = isQ ? QSCALE : 1.0f;
        int obase = n0 & 1023;
#pragma unroll
        for (int i = 0; i < 2; i++)
#pragma unroll
            for (int j = 0; j < 2; j++) {
                int o = obase + wn + j * 32 + e31;
                int h = o >> 6, d = o & 63;
#pragma unroll
                for (int r = 0; r < 16; r++) {
                    int trow = m0 + wm + i * 32 + (r & 3) + 8 * (r >> 2) + 4 * h2;
                    dst[((size_t)(h * T_SEQ + trow)) * 64 + d] = (bf16)(acc[i][j][r] * scale);
                }
            }
    } else {
        int obase = n0 - 2048;
#pragma unroll
        for (int i = 0; i < 2; i++)
#pragma unroll
            for (int j = 0; j < 2; j++) {
                int o = obase + wn + j * 32 + e31;       // h*64+d
                size_t base = (size_t)o * T_SEQ;
#pragma unroll
                for (int rq = 0; rq < 4; rq++) {
                    int tbase = m0 + wm + i * 32 + 8 * rq + 4 * h2;
                    bf16x4 pk;
#pragma unroll
                    for (int rr = 0; rr < 4; rr++) pk[rr] = (bf16)acc[i][j][rq * 4 + rr];
                    *(bf16x4*)(vtb + base + tbase) = pk;
                }
            }
    }
}

// ---------------------------------------------------------------------------
// Banded attention, 32x32 MFMA: block = (head, 128 q-rows), 4 waves of 32
// queries; per-wave key window [rowbase-128, rowbase+32) = 5 x 32 key tiles.
// S^T = K.Q^T (A=K m=key, B=Q n=query): C/D col = query = lane&31 -> softmax
// fully in-lane over 80 keys + ONE xor-32 shuffle; 1/l folded into P.
// PV: P (A, m=query) from per-wave LDS, V^T (B, n=d) from global.
// Q pre-scaled by 0.125*log2e -> pure exp2. Prologue: Wo fp32->bf16.
// ---------------------------------------------------------------------------
#define PSTR 168   // 160 keys + 8 pad

__global__ __launch_bounds__(256) void attn(
        const bf16* __restrict__ qbuf, const bf16* __restrict__ kbuf,
        const bf16* __restrict__ vtbuf, bf16* __restrict__ yb,
        const float* __restrict__ wo, bf16* __restrict__ wob) {
    __shared__ __align__(16) bf16 p_lds[4 * 32 * PSTR];   // 43 KB
    int t = threadIdx.x;
    int w = t >> 6, l = t & 63;
    int e31 = l & 31, h2 = l >> 5;

    {   // Wo conversion: 512 blocks x 256 thr x 8 = 1048576 exactly
        size_t g = ((size_t)blockIdx.x * 256 + t) * 8;
        const float4* sv = (const float4*)(wo + g);
        float4 a = sv[0], b = sv[1];
        bf16x8 o8;
        o8[0] = (bf16)a.x; o8[1] = (bf16)a.y; o8[2] = (bf16)a.z; o8[3] = (bf16)a.w;
        o8[4] = (bf16)b.x; o8[5] = (bf16)b.y; o8[6] = (bf16)b.z; o8[7] = (bf16)b.w;
        *(bf16x8*)(wob + g) = o8;
    }

    int h = blockIdx.x >> 5;
    int qt = blockIdx.x & 31;
    int i0 = qt * 128;
    int rowbase = i0 + w * 32;        // wave's 32 queries
    int jbase = rowbase - 128;        // 160-key window start

    const bf16* Q  = qbuf  + (size_t)h * T_SEQ * 64;
    const bf16* Kp = kbuf  + (size_t)h * T_SEQ * 64;
    const bf16* Vt = vtbuf + (size_t)h * 64 * T_SEQ;

    // Q fragments (B-operand): n = query = rowbase+e31, k = kk*16 + h2*8 + j
    bf16x8 qf[4];
#pragma unroll
    for (int kk = 0; kk < 4; kk++)
        qf[kk] = *(const bf16x8*)(Q + (size_t)(rowbase + e31) * 64 + kk * 16 + h2 * 8);

    // S^T: 5 key tiles of 32; A = K (m = key = jbase + mi*32 + e31)
    f32x16 st[5];
#pragma unroll
    for (int mi = 0; mi < 5; mi++)
#pragma unroll
        for (int r = 0; r < 16; r++) st[mi][r] = 0.f;
#pragma unroll
    for (int mi = 0; mi < 5; mi++) {
        int jr = jbase + mi * 32 + e31;
        int jl = jr < 0 ? 0 : jr;
        const bf16* kr = Kp + (size_t)jl * 64 + h2 * 8;
#pragma unroll
        for (int kk = 0; kk < 4; kk++) {
            bf16x8 kf = *(const bf16x8*)(kr + kk * 16);
            st[mi] = __builtin_amdgcn_mfma_f32_32x32x16_bf16(kf, qf[kk], st[mi], 0, 0, 0);
        }
    }

    // per-query softmax: lane's query = rowbase+e31; lane holds keys
    // jbase + mi*32 + (r&3)+8*(r>>2)+4*h2 (80 of 160; partner lane has rest)
    int ii = rowbase + e31;
    float rs = 0.f;
#pragma unroll
    for (int mi = 0; mi < 5; mi++)
#pragma unroll
        for (int r = 0; r < 16; r++) {
            int jj = jbase + mi * 32 + (r & 3) + 8 * (r >> 2) + 4 * h2;
            bool ok = (jj >= 0) && ((unsigned)(ii - jj) < (unsigned)BAND);
            float p = ok ? __builtin_amdgcn_exp2f(st[mi][r]) : 0.f;
            st[mi][r] = p;
            rs += p;
        }
    rs += __shfl_xor(rs, 32);
    float inv = 1.0f / rs;

    // P -> per-wave LDS, normalized; packed bf16x4 (key quads contiguous)
    bf16* qrow = p_lds + (w * 32 + e31) * PSTR;
#pragma unroll
    for (int mi = 0; mi < 5; mi++)
#pragma unroll
        for (int rq = 0; rq < 4; rq++) {
            bf16x4 pk;
#pragma unroll
            for (int rr = 0; rr < 4; rr++) pk[rr] = (bf16)(st[mi][rq * 4 + rr] * inv);
            *(bf16x4*)(qrow + mi * 32 + 8 * rq + 4 * h2) = pk;
        }

    // O = P(32q x 160k) V(160k x 64d): A=P (m=query), B=Vt (n=d), 10 k-chunks
    f32x16 oacc[2];
#pragma unroll
    for (int di = 0; di < 2; di++)
#pragma unroll
        for (int r = 0; r < 16; r++) oacc[di][r] = 0.f;
#pragma unroll
    for (int kc = 0; kc < 10; kc++) {
        bf16x8 pf = *(const bf16x8*)(qrow + kc * 16 + h2 * 8);
        int jv = jbase + kc * 16 + h2 * 8;
        int jvc = jv < 0 ? 0 : jv;       // P = 0 there
#pragma unroll
        for (int di = 0; di < 2; di++) {
            bf16x8 vf = *(const bf16x8*)(Vt + (size_t)(di * 32 + e31) * T_SEQ + jvc);
            oacc[di] = __builtin_amdgcn_mfma_f32_32x32x16_bf16(pf, vf, oacc[di], 0, 0, 0);
        }
    }

    // y store: col = d = di*32+e31, row = query = (r&3)+8*(r>>2)+4*h2
#pragma unroll
    for (int di = 0; di < 2; di++)
#pragma unroll
        for (int r = 0; r < 16; r++) {
            int tt = rowbase + (r & 3) + 8 * (r >> 2) + 4 * h2;
            int c = h * 64 + di * 32 + e31;
            yb[(size_t)tt * CDIM + c] = (bf16)oacc[di][r];
        }
}

// ---------------------------------------------------------------------------
// Output projection: out[t,o] = sum_c y[t,c]*Wo[o,c], fp32 out.
// 64x128 tile, BK=64 -> 512 blocks; 4 waves as 2x2 of (32m x 64n); 32x32x16.
// ---------------------------------------------------------------------------
__global__ __launch_bounds__(256) void gemm_proj(
        const bf16* __restrict__ A, const bf16* __restrict__ B,
        float* __restrict__ Cout) {
    const int K = 1024;
    __shared__ __align__(16) bf16 lds_a[64 * 64];
    __shared__ __align__(16) bf16 lds_b[128 * 64];
    int t = threadIdx.x;
    int w = t >> 6, l = t & 63;
    int e31 = l & 31, h2 = l >> 5;
    int bx = blockIdx.x;
    int bm = bx & 63, bn = bx >> 6;          // 64 x 8 blocks
    int m0 = bm * 64, n0 = bn * 128;
    int wm = (w >> 1) * 32, wn = (w & 1) * 64;

    f32x16 acc[2];
#pragma unroll
    for (int j = 0; j < 2; j++)
#pragma unroll
        for (int r = 0; r < 16; r++) acc[j][r] = 0.f;

    int rowA[2], koA[2], rowB[4], koB[4];
#pragma unroll
    for (int it = 0; it < 2; it++) {
        int cid = it * 256 + t;
        rowA[it] = cid >> 3;
        koA[it] = ((cid & 7) ^ (rowA[it] & 7)) * 8;
    }
#pragma unroll
    for (int it = 0; it < 4; it++) {
        int cid = it * 256 + t;
        rowB[it] = cid >> 3;
        koB[it] = ((cid & 7) ^ (rowB[it] & 7)) * 8;
    }
    int rowa = wm + e31;
    int rowb0 = wn + e31, rowb1 = wn + 32 + e31;
    int sa = rowa & 7, sb0 = rowb0 & 7, sb1 = rowb1 & 7;
    const bf16* ba = lds_a + rowa * 64;
    const bf16* bb0 = lds_b + rowb0 * 64;
    const bf16* bb1 = lds_b + rowb1 * 64;

    for (int k0 = 0; k0 < K; k0 += 64) {
#pragma unroll
        for (int it = 0; it < 2; it++)
            async_ld16(A + (size_t)(m0 + rowA[it]) * K + k0 + koA[it],
                       lds_a + (it * 256 + w * 64) * 8);
#pragma unroll
        for (int it = 0; it < 4; it++)
            async_ld16(B + (size_t)(n0 + rowB[it]) * K + k0 + koB[it],
                       lds_b + (it * 256 + w * 64) * 8);
        __syncthreads();
#pragma unroll
        for (int kk = 0; kk < 4; kk++) {
            int lc = kk * 2 + h2;
            bf16x8 af = *(const bf16x8*)(ba + ((lc ^ sa) * 8));
            bf16x8 b0 = *(const bf16x8*)(bb0 + ((lc ^ sb0) * 8));
            bf16x8 b1 = *(const bf16x8*)(bb1 + ((lc ^ sb1) * 8));
            acc[0] = __builtin_amdgcn_mfma_f32_32x32x16_bf16(af, b0, acc[0], 0, 0, 0);
            acc[1] = __builtin_amdgcn_mfma_f32_32x32x16_bf16(af, b1, acc[1], 0, 0, 0);
        }
        __syncthreads();
    }
#pragma unroll
    for (int j = 0; j < 2; j++) {
        int ncol = n0 + wn + j * 32 + e31;
#pragma unroll
        for (int r = 0; r < 16; r++) {
            int trow = m0 + wm + (r & 3) + 8 * (r >> 2) + 4 * h2;
            Cout[(size_t)trow * CDIM + ncol] = acc[j][r];
        }
    }
}

extern "C" void kernel_launch(void* const* d_in, const int* in_sizes, int n_in,
                              void* d_out, int out_size, void* d_ws, size_t ws_size,
                              hipStream_t stream) {
    const float* x  = (const float*)d_in[0];
    const float* Wq = (const float*)d_in[1];
    const float* Wk = (const float*)d_in[2];
    const float* Wv = (const float*)d_in[3];
    const float* Wo = (const float*)d_in[4];
    float* out = (float*)d_out;

    char* ws = (char*)d_ws;
    bf16* xb    = (bf16*)(ws);                        //  8 MB  x bf16
    bf16* wqkvb = (bf16*)(ws + ((size_t)8  << 20));   //  6 MB  [Wq;Wk;Wv]
    bf16* wob   = (bf16*)(ws + ((size_t)14 << 20));   //  2 MB  Wo
    bf16* qb    = (bf16*)(ws + ((size_t)16 << 20));   //  8 MB  Q (H,T,64), pre-scaled
    bf16* kb    = (bf16*)(ws + ((size_t)24 << 20));   //  8 MB  K (H,T,64)
    bf16* vtb   = (bf16*)(ws + ((size_t)32 << 20));   //  8 MB  V^T (H*64,T)
    bf16* yb    = (bf16*)(ws + ((size_t)40 << 20));   //  8 MB  y (T,C)

    cvt_all<<<3584, 256, 0, stream>>>(x, Wq, Wk, Wv, xb, wqkvb);
    gemm_qkv<<<768, 256, 0, stream>>>(xb, wqkvb, qb, kb, vtb);
    attn<<<512, 256, 0, stream>>>(qb, kb, vtb, yb, Wo, wob);
    gemm_proj<<<512, 256, 0, stream>>>(yb, wob, out);
}

// Round 9
// 145.225 us; speedup vs baseline: 1.0479x; 1.0020x over previous
//
#include <hip/hip_runtime.h>
#include <hip/hip_bf16.h>
#include <stdint.h>

#define T_SEQ 4096
#define CDIM  1024
#define NH    16
#define DHEAD 64
#define BAND  128

typedef __bf16 bf16;
typedef __attribute__((ext_vector_type(8)))  __bf16 bf16x8;
typedef __attribute__((ext_vector_type(4)))  __bf16 bf16x4;
typedef __attribute__((ext_vector_type(4)))  float  f32x4;
typedef __attribute__((ext_vector_type(16))) float  f32x16;

// 0.125 (1/sqrt(64)) * log2(e): folded into Q so attn softmax is pure exp2
#define QSCALE 0.1803368801111204f

__device__ __forceinline__ void async_ld16(const bf16* g, bf16* l) {
    __builtin_amdgcn_global_load_lds(
        (__attribute__((address_space(1))) void*)g,
        (__attribute__((address_space(3))) void*)l, 16, 0, 0);
}

// ---------------------------------------------------------------------------
// fp32 -> bf16, 8 elems/thread: x (4194304) + [Wq;Wk;Wv] (3145728)
// ---------------------------------------------------------------------------
__global__ void cvt_all(const float* __restrict__ x,  const float* __restrict__ wq,
                        const float* __restrict__ wk, const float* __restrict__ wv,
                        bf16* __restrict__ xb, bf16* __restrict__ wqkvb) {
    size_t g = (size_t)blockIdx.x * 256 + threadIdx.x;
    const float* s; bf16* d;
    if (g < 524288) {
        s = x + g * 8; d = xb + g * 8;
    } else {
        size_t i2 = (g - 524288) * 8;
        int which = (int)(i2 >> 20);
        s = ((which == 0) ? wq : (which == 1) ? wk : wv) + (i2 & 1048575);
        d = wqkvb + i2;
    }
    const float4* sv = (const float4*)s;
    float4 a = sv[0], b = sv[1];
    bf16x8 o;
    o[0] = (bf16)a.x; o[1] = (bf16)a.y; o[2] = (bf16)a.z; o[3] = (bf16)a.w;
    o[4] = (bf16)b.x; o[5] = (bf16)b.y; o[6] = (bf16)b.z; o[7] = (bf16)b.w;
    *(bf16x8*)d = o;
}

// ---------------------------------------------------------------------------
// QKV GEMM: C[m,n] = sum_k A[m,k]*B[n,k]   A=4096x1024 (x), B=3072x1024
// 128x128 tile, BK=64, 4 waves (2x2 of 64x64), 32x32x16 bf16 MFMA,
// 8-slot XOR-swizzled LDS rows (conflict-free b128 frag reads).
// ---------------------------------------------------------------------------
__global__ __launch_bounds__(256) void gemm_qkv(
        const bf16* __restrict__ A, const bf16* __restrict__ B,
        bf16* __restrict__ qb, bf16* __restrict__ kb, bf16* __restrict__ vtb) {
    const int K = 1024;
    __shared__ __align__(16) bf16 lds_a[128 * 64];
    __shared__ __align__(16) bf16 lds_b[128 * 64];
    int t = threadIdx.x;
    int w = t >> 6, l = t & 63;
    int e31 = l & 31, h2 = l >> 5;
    int bx = blockIdx.x;
    int bm = bx & 31, bn = bx >> 5;          // 32 x 24 blocks
    int m0 = bm * 128, n0 = bn * 128;
    int wm = (w >> 1) * 64, wn = (w & 1) * 64;

    f32x16 acc[2][2];
#pragma unroll
    for (int i = 0; i < 2; i++)
#pragma unroll
        for (int j = 0; j < 2; j++)
#pragma unroll
            for (int r = 0; r < 16; r++) acc[i][j][r] = 0.f;

    int row_s[4], ko_s[4];
#pragma unroll
    for (int it = 0; it < 4; it++) {
        int cid = it * 256 + t;
        row_s[it] = cid >> 3;
        ko_s[it] = ((cid & 7) ^ (row_s[it] & 7)) * 8;
    }
    int rowa0 = wm + e31, rowa1 = wm + 32 + e31;
    int rowb0 = wn + e31, rowb1 = wn + 32 + e31;
    int sa0 = rowa0 & 7, sa1 = rowa1 & 7, sb0 = rowb0 & 7, sb1 = rowb1 & 7;
    const bf16* ba0 = lds_a + rowa0 * 64;
    const bf16* ba1 = lds_a + rowa1 * 64;
    const bf16* bb0 = lds_b + rowb0 * 64;
    const bf16* bb1 = lds_b + rowb1 * 64;

    for (int k0 = 0; k0 < K; k0 += 64) {
#pragma unroll
        for (int it = 0; it < 4; it++) {
            bf16* dst_a = lds_a + (it * 256 + w * 64) * 8;
            bf16* dst_b = lds_b + (it * 256 + w * 64) * 8;
            async_ld16(A + (size_t)(m0 + row_s[it]) * K + k0 + ko_s[it], dst_a);
            async_ld16(B + (size_t)(n0 + row_s[it]) * K + k0 + ko_s[it], dst_b);
        }
        __syncthreads();
#pragma unroll
        for (int kk = 0; kk < 4; kk++) {
            int lc = kk * 2 + h2;
            bf16x8 a0 = *(const bf16x8*)(ba0 + ((lc ^ sa0) * 8));
            bf16x8 a1 = *(const bf16x8*)(ba1 + ((lc ^ sa1) * 8));
            bf16x8 b0 = *(const bf16x8*)(bb0 + ((lc ^ sb0) * 8));
            bf16x8 b1 = *(const bf16x8*)(bb1 + ((lc ^ sb1) * 8));
            acc[0][0] = __builtin_amdgcn_mfma_f32_32x32x16_bf16(a0, b0, acc[0][0], 0, 0, 0);
            acc[0][1] = __builtin_amdgcn_mfma_f32_32x32x16_bf16(a0, b1, acc[0][1], 0, 0, 0);
            acc[1][0] = __builtin_amdgcn_mfma_f32_32x32x16_bf16(a1, b0, acc[1][0], 0, 0, 0);
            acc[1][1] = __builtin_amdgcn_mfma_f32_32x32x16_bf16(a1, b1, acc[1][1], 0, 0, 0);
        }
        __syncthreads();
    }

    if (n0 < 2048) {
        bool isQ = (n0 < 1024);
        bf16* dst = isQ ? qb : kb;
        float scale = isQ ? QSCALE : 1.0f;
        int obase = n0 & 1023;
#pragma unroll
        for (int i = 0; i < 2; i++)
#pragma unroll
            for (int j = 0; j < 2; j++) {
                int o = obase + wn + j * 32 + e31;
                int h = o >> 6, d = o & 63;
#pragma unroll
                for (int r = 0; r < 16; r++) {
                    int trow = m0 + wm + i * 32 + (r & 3) + 8 * (r >> 2) + 4 * h2;
                    dst[((size_t)(h * T_SEQ + trow)) * 64 + d] = (bf16)(acc[i][j][r] * scale);
                }
            }
    } else {
        int obase = n0 - 2048;
#pragma unroll
        for (int i = 0; i < 2; i++)
#pragma unroll
            for (int j = 0; j < 2; j++) {
                int o = obase + wn + j * 32 + e31;       // h*64+d
                size_t base = (size_t)o * T_SEQ;
#pragma unroll
                for (int rq = 0; rq < 4; rq++) {
                    int tbase = m0 + wm + i * 32 + 8 * rq + 4 * h2;
                    bf16x4 pk;
#pragma unroll
                    for (int rr = 0; rr < 4; rr++) pk[rr] = (bf16)acc[i][j][rq * 4 + rr];
                    *(bf16x4*)(vtb + base + tbase) = pk;
                }
            }
    }
}

// ---------------------------------------------------------------------------
// Banded attention, 32x32 MFMA: block = (head, 128 q-rows), 4 waves of 32
// queries; per-wave key window [rowbase-128, rowbase+32) = 5 x 32 key tiles.
// S^T = K.Q^T (A=K m=key, B=Q n=query): C/D col = query = lane&31 -> softmax
// fully in-lane over 80 keys + ONE xor-32 shuffle; 1/l folded into P.
// FAST PATH (rowbase>=128, 31/32 of blocks): tiles mi=1..3 are provably
// fully live (max ii-jj = 127, min = 1); tiles mi=0 / mi=4 have
// COMPLEMENTARY lane-local masks: live(mi0) <=> key_off > e31,
// live(mi4) <=> key_off <= e31  ->  one exp2 on the selected input,
// split p into P0/P4. 64 exp2 + ~50 mask VALU vs 80 + ~320.
// Q pre-scaled by 0.125*log2e -> pure exp2. Prologue: Wo fp32->bf16.
// ---------------------------------------------------------------------------
#define PSTR 168   // 160 keys + 8 pad

__global__ __launch_bounds__(256) void attn(
        const bf16* __restrict__ qbuf, const bf16* __restrict__ kbuf,
        const bf16* __restrict__ vtbuf, bf16* __restrict__ yb,
        const float* __restrict__ wo, bf16* __restrict__ wob) {
    __shared__ __align__(16) bf16 p_lds[4 * 32 * PSTR];   // 43 KB
    int t = threadIdx.x;
    int w = t >> 6, l = t & 63;
    int e31 = l & 31, h2 = l >> 5;

    {   // Wo conversion: 512 blocks x 256 thr x 8 = 1048576 exactly
        size_t g = ((size_t)blockIdx.x * 256 + t) * 8;
        const float4* sv = (const float4*)(wo + g);
        float4 a = sv[0], b = sv[1];
        bf16x8 o8;
        o8[0] = (bf16)a.x; o8[1] = (bf16)a.y; o8[2] = (bf16)a.z; o8[3] = (bf16)a.w;
        o8[4] = (bf16)b.x; o8[5] = (bf16)b.y; o8[6] = (bf16)b.z; o8[7] = (bf16)b.w;
        *(bf16x8*)(wob + g) = o8;
    }

    int h = blockIdx.x >> 5;
    int qt = blockIdx.x & 31;
    int i0 = qt * 128;
    int rowbase = i0 + w * 32;        // wave's 32 queries
    int jbase = rowbase - 128;        // 160-key window start

    const bf16* Q  = qbuf  + (size_t)h * T_SEQ * 64;
    const bf16* Kp = kbuf  + (size_t)h * T_SEQ * 64;
    const bf16* Vt = vtbuf + (size_t)h * 64 * T_SEQ;

    // Q fragments (B-operand): n = query = rowbase+e31, k = kk*16 + h2*8 + j
    bf16x8 qf[4];
#pragma unroll
    for (int kk = 0; kk < 4; kk++)
        qf[kk] = *(const bf16x8*)(Q + (size_t)(rowbase + e31) * 64 + kk * 16 + h2 * 8);

    // S^T: 5 key tiles of 32; A = K (m = key = jbase + mi*32 + e31)
    f32x16 st[5];
#pragma unroll
    for (int mi = 0; mi < 5; mi++)
#pragma unroll
        for (int r = 0; r < 16; r++) st[mi][r] = 0.f;
#pragma unroll
    for (int mi = 0; mi < 5; mi++) {
        int jr = jbase + mi * 32 + e31;
        int jl = jr < 0 ? 0 : jr;
        const bf16* kr = Kp + (size_t)jl * 64 + h2 * 8;
#pragma unroll
        for (int kk = 0; kk < 4; kk++) {
            bf16x8 kf = *(const bf16x8*)(kr + kk * 16);
            st[mi] = __builtin_amdgcn_mfma_f32_32x32x16_bf16(kf, qf[kk], st[mi], 0, 0, 0);
        }
    }

    // per-query softmax (lane's query = rowbase+e31; lane holds keys
    // jbase + mi*32 + key_off, key_off = (r&3)+8*(r>>2)+4*h2)
    float rs = 0.f;
    if (rowbase >= 128) {
        // fast path: mi=1..3 unconditional
#pragma unroll
        for (int mi = 1; mi < 4; mi++)
#pragma unroll
            for (int r = 0; r < 16; r++) {
                float p = __builtin_amdgcn_exp2f(st[mi][r]);
                st[mi][r] = p;
                rs += p;
            }
        // mi=0 / mi=4: complementary masks, one exp2 per r
#pragma unroll
        for (int r = 0; r < 16; r++) {
            int key_off = (r & 3) + 8 * (r >> 2) + 4 * h2;
            bool first = key_off > e31;            // live in mi=0, else mi=4
            float sv = first ? st[0][r] : st[4][r];
            float p = __builtin_amdgcn_exp2f(sv);
            rs += p;
            float p0 = first ? p : 0.f;
            st[0][r] = p0;
            st[4][r] = p - p0;
        }
    } else {
        int ii = rowbase + e31;
#pragma unroll
        for (int mi = 0; mi < 5; mi++)
#pragma unroll
            for (int r = 0; r < 16; r++) {
                int jj = jbase + mi * 32 + (r & 3) + 8 * (r >> 2) + 4 * h2;
                bool ok = (jj >= 0) && ((unsigned)(ii - jj) < (unsigned)BAND);
                float p = ok ? __builtin_amdgcn_exp2f(st[mi][r]) : 0.f;
                st[mi][r] = p;
                rs += p;
            }
    }
    rs += __shfl_xor(rs, 32);
    float inv = 1.0f / rs;

    // P -> per-wave LDS, normalized; packed bf16x4 (key quads contiguous)
    bf16* qrow = p_lds + (w * 32 + e31) * PSTR;
#pragma unroll
    for (int mi = 0; mi < 5; mi++)
#pragma unroll
        for (int rq = 0; rq < 4; rq++) {
            bf16x4 pk;
#pragma unroll
            for (int rr = 0; rr < 4; rr++) pk[rr] = (bf16)(st[mi][rq * 4 + rr] * inv);
            *(bf16x4*)(qrow + mi * 32 + 8 * rq + 4 * h2) = pk;
        }

    // O = P(32q x 160k) V(160k x 64d): A=P (m=query), B=Vt (n=d), 10 k-chunks
    f32x16 oacc[2];
#pragma unroll
    for (int di = 0; di < 2; di++)
#pragma unroll
        for (int r = 0; r < 16; r++) oacc[di][r] = 0.f;
#pragma unroll
    for (int kc = 0; kc < 10; kc++) {
        bf16x8 pf = *(const bf16x8*)(qrow + kc * 16 + h2 * 8);
        int jv = jbase + kc * 16 + h2 * 8;
        int jvc = jv < 0 ? 0 : jv;       // P = 0 there
#pragma unroll
        for (int di = 0; di < 2; di++) {
            bf16x8 vf = *(const bf16x8*)(Vt + (size_t)(di * 32 + e31) * T_SEQ + jvc);
            oacc[di] = __builtin_amdgcn_mfma_f32_32x32x16_bf16(pf, vf, oacc[di], 0, 0, 0);
        }
    }

    // y store: col = d = di*32+e31, row = query = (r&3)+8*(r>>2)+4*h2
#pragma unroll
    for (int di = 0; di < 2; di++)
#pragma unroll
        for (int r = 0; r < 16; r++) {
            int tt = rowbase + (r & 3) + 8 * (r >> 2) + 4 * h2;
            int c = h * 64 + di * 32 + e31;
            yb[(size_t)tt * CDIM + c] = (bf16)oacc[di][r];
        }
}

// ---------------------------------------------------------------------------
// Output projection: out[t,o] = sum_c y[t,c]*Wo[o,c], fp32 out.
// 64x128 tile, BK=64 -> 512 blocks; 4 waves as 2x2 of (32m x 64n); 32x32x16.
// ---------------------------------------------------------------------------
__global__ __launch_bounds__(256) void gemm_proj(
        const bf16* __restrict__ A, const bf16* __restrict__ B,
        float* __restrict__ Cout) {
    const int K = 1024;
    __shared__ __align__(16) bf16 lds_a[64 * 64];
    __shared__ __align__(16) bf16 lds_b[128 * 64];
    int t = threadIdx.x;
    int w = t >> 6, l = t & 63;
    int e31 = l & 31, h2 = l >> 5;
    int bx = blockIdx.x;
    int bm = bx & 63, bn = bx >> 6;          // 64 x 8 blocks
    int m0 = bm * 64, n0 = bn * 128;
    int wm = (w >> 1) * 32, wn = (w & 1) * 64;

    f32x16 acc[2];
#pragma unroll
    for (int j = 0; j < 2; j++)
#pragma unroll
        for (int r = 0; r < 16; r++) acc[j][r] = 0.f;

    int rowA[2], koA[2], rowB[4], koB[4];
#pragma unroll
    for (int it = 0; it < 2; it++) {
        int cid = it * 256 + t;
        rowA[it] = cid >> 3;
        koA[it] = ((cid & 7) ^ (rowA[it] & 7)) * 8;
    }
#pragma unroll
    for (int it = 0; it < 4; it++) {
        int cid = it * 256 + t;
        rowB[it] = cid >> 3;
        koB[it] = ((cid & 7) ^ (rowB[it] & 7)) * 8;
    }
    int rowa = wm + e31;
    int rowb0 = wn + e31, rowb1 = wn + 32 + e31;
    int sa = rowa & 7, sb0 = rowb0 & 7, sb1 = rowb1 & 7;
    const bf16* ba = lds_a + rowa * 64;
    const bf16* bb0 = lds_b + rowb0 * 64;
    const bf16* bb1 = lds_b + rowb1 * 64;

    for (int k0 = 0; k0 < K; k0 += 64) {
#pragma unroll
        for (int it = 0; it < 2; it++)
            async_ld16(A + (size_t)(m0 + rowA[it]) * K + k0 + koA[it],
                       lds_a + (it * 256 + w * 64) * 8);
#pragma unroll
        for (int it = 0; it < 4; it++)
            async_ld16(B + (size_t)(n0 + rowB[it]) * K + k0 + koB[it],
                       lds_b + (it * 256 + w * 64) * 8);
        __syncthreads();
#pragma unroll
        for (int kk = 0; kk < 4; kk++) {
            int lc = kk * 2 + h2;
            bf16x8 af = *(const bf16x8*)(ba + ((lc ^ sa) * 8));
            bf16x8 b0 = *(const bf16x8*)(bb0 + ((lc ^ sb0) * 8));
            bf16x8 b1 = *(const bf16x8*)(bb1 + ((lc ^ sb1) * 8));
            acc[0] = __builtin_amdgcn_mfma_f32_32x32x16_bf16(af, b0, acc[0], 0, 0, 0);
            acc[1] = __builtin_amdgcn_mfma_f32_32x32x16_bf16(af, b1, acc[1], 0, 0, 0);
        }
        __syncthreads();
    }
#pragma unroll
    for (int j = 0; j < 2; j++) {
        int ncol = n0 + wn + j * 32 + e31;
#pragma unroll
        for (int r = 0; r < 16; r++) {
            int trow = m0 + wm + (r & 3) + 8 * (r >> 2) + 4 * h2;
            Cout[(size_t)trow * CDIM + ncol] = acc[j][r];
        }
    }
}

extern "C" void kernel_launch(void* const* d_in, const int* in_sizes, int n_in,
                              void* d_out, int out_size, void* d_ws, size_t ws_size,
                              hipStream_t stream) {
    const float* x  = (const float*)d_in[0];
    const float* Wq = (const float*)d_in[1];
    const float* Wk = (const float*)d_in[2];
    const float* Wv = (const float*)d_in[3];
    const float* Wo = (const float*)d_in[4];
    float* out = (float*)d_out;

    char* ws = (char*)d_ws;
    bf16* xb    = (bf16*)(ws);                        //  8 MB  x bf16
    bf16* wqkvb = (bf16*)(ws + ((size_t)8  << 20));   //  6 MB  [Wq;Wk;Wv]
    bf16* wob   = (bf16*)(ws + ((size_t)14 << 20));   //  2 MB  Wo
    bf16* qb    = (bf16*)(ws + ((size_t)16 << 20));   //  8 MB  Q (H,T,64), pre-scaled
    bf16* kb    = (bf16*)(ws + ((size_t)24 << 20));   //  8 MB  K (H,T,64)
    bf16* vtb   = (bf16*)(ws + ((size_t)32 << 20));   //  8 MB  V^T (H*64,T)
    bf16* yb    = (bf16*)(ws + ((size_t)40 << 20));   //  8 MB  y (T,C)

    cvt_all<<<3584, 256, 0, stream>>>(x, Wq, Wk, Wv, xb, wqkvb);
    gemm_qkv<<<768, 256, 0, stream>>>(xb, wqkvb, qb, kb, vtb);
    attn<<<512, 256, 0, stream>>>(qb, kb, vtb, yb, Wo, wob);
    gemm_proj<<<512, 256, 0, stream>>>(yb, wob, out);
}